// Round 14
// baseline (157.751 us; speedup 1.0000x reference)
//
#include <hip/hip_runtime.h>
#include <hip/hip_bf16.h>
#include <math.h>

// Loss_26886495273741: uniformity loss
//   dots = F F^T (diag masked), I = argmax_row(dots), d = ||x - x_nn + eps||_2
//   loss = -mean(log(n*d))
// F: [16384, 256] fp32.
//
// Round 14: occupancy push. R13 chassis with ONE change: B slices K=64 -> K=32
//   so LDS = 32768 (A) + 2x4096 (B dbuf) = 40960 B exactly -> 4 blocks/CU
//   (was 3). Rationale: R13 counters show MfmaUtil~VALUBusy~LDS all ~35%
//   (no pipe saturated) = latency-bound at 3 waves/SIMD; +1 block/CU adds
//   TLP to overlap MFMA / fold-VALU / ds_read / barrier-drain phases.
//   Cost: 8 barriers/tile (was 4) -- the single experimental variable.
//   Everything else (folds, in-loop unique-address scratch atomics, K0,
//   scan, K2) is R13-verbatim.

#define NROWS 16384
#define DIM   256
#define EPSF  1e-6f

typedef __attribute__((ext_vector_type(4))) float f32x4;

typedef const __attribute__((address_space(1))) void* gas1_t;
typedef __attribute__((address_space(3))) void* las3_t;

__device__ __forceinline__ void glds16(const void* g, void* l) {
    __builtin_amdgcn_global_load_lds((gas1_t)g, (las3_t)l, 16, 0, 0);
}

__device__ __forceinline__ unsigned umax2(unsigned a, unsigned b) {
    return a > b ? a : b;
}

__device__ __forceinline__ unsigned long long umax64(unsigned long long a,
                                                     unsigned long long b) {
    return a > b ? a : b;
}

// RNE fp32 -> OCP e4m3fn (subnormal cutoff at 2^-6; codes continuous at seam)
__device__ __forceinline__ unsigned f2e4m3(float f) {
    union { float f; unsigned u; } x; x.f = f;
    const unsigned s = (x.u >> 24) & 0x80u;
    const unsigned au = x.u & 0x7FFFFFFFu;
    const float af = __uint_as_float(au);
    if (au < 0x3C800000u) {                    // |x| < 2^-6: subnormal region
        const int q = (int)(af * 512.0f + 0.5f);   // LSB = 2^-9
        return s | (unsigned)q;
    }
    const unsigned add = 0x7FFFFu + ((au >> 20) & 1u);
    const unsigned v = au + add;
    const unsigned e = (v >> 23) - 120u;       // e4m3 exponent (bias 7), e>=1
    return s | (e << 3) | ((v >> 20) & 7u);
}

// -------- K0: convert fp32 -> fp8 e4m3, zero packed + scratch --------
__global__ __launch_bounds__(256)
void convert_kernel(const float* __restrict__ F, unsigned char* __restrict__ F8,
                    unsigned long long* __restrict__ packed,
                    unsigned long long* __restrict__ scratch)
{
    const int t = blockIdx.x * 256 + threadIdx.x;     // 524288 threads
    const float4 a = *reinterpret_cast<const float4*>(F + (size_t)t * 8);
    const float4 b = *reinterpret_cast<const float4*>(F + (size_t)t * 8 + 4);
    const unsigned lo = f2e4m3(a.x) | (f2e4m3(a.y) << 8) |
                        (f2e4m3(a.z) << 16) | (f2e4m3(a.w) << 24);
    const unsigned hi = f2e4m3(b.x) | (f2e4m3(b.y) << 8) |
                        (f2e4m3(b.z) << 16) | (f2e4m3(b.w) << 24);
    uint2 v; v.x = lo; v.y = hi;
    *reinterpret_cast<uint2*>(F8 + (size_t)t * 8) = v;
    if (t < NROWS) packed[t] = 0ull;
    #pragma unroll
    for (int q = 0; q < 4; ++q)                       // 2M u64 = 16 MB
        scratch[(size_t)t * 4 + q] = 0ull;
}

// -------- K1: symmetric fp8 MFMA + two-sided argmax (K=32 slices) --------
__global__ __launch_bounds__(256, 4)
void mfma_sym_fp8_kernel(const unsigned char* __restrict__ F8,
                         unsigned long long* __restrict__ packed,
                         unsigned long long* __restrict__ scratch)
{
    __shared__ __align__(16) unsigned char As[32768];   // [k16 0..15][row][16B]
    __shared__ __align__(16) unsigned char Bs[2 * 4096];// 2 x [k16 0..1][col][16B]

    const int tid  = threadIdx.x;
    const int w    = tid >> 6;
    const int l    = tid & 63;
    const int rs   = (int)blockIdx.x >> 3;      // row stripe 0..127
    const int ck   = (int)blockIdx.x & 7;       // chunk-of-stripe 0..7
    const int span = 128 - rs;
    const int t0   = rs + (span * ck) / 8;
    const int t1   = rs + (span * (ck + 1)) / 8;
    if (t0 >= t1) return;                       // block-uniform

    const int row0 = rs * 128;
    const int wrow = (w >> 1) * 64;
    const int wcol = (w & 1) * 64;
    const int lc   = l & 15;
    const int lr4  = l >> 4;

    // ---- stage A panel: 32 issues, cell q*64+l -> [k16=q>>1][row=(q&1)*64+l] ----
    #pragma unroll
    for (int m = 0; m < 8; ++m) {
        const int q   = 8 * w + m;              // 0..31
        const int k16 = q >> 1;
        const int row = (q & 1) * 64 + l;
        glds16(F8 + (size_t)(row0 + row) * DIM + k16 * 16, &As[q * 1024]);
    }

    // ---- stage first B slice (t0, slice 0) into slot 0: 1 issue/thread ----
    // cell tid: k16 = tid>>7 (0..1), col = tid&127
    glds16(F8 + (size_t)(t0 * 128 + (tid & 127)) * DIM + (tid >> 7) * 16,
           &Bs[tid * 16]);

    const long* __restrict__ Al = reinterpret_cast<const long*>(As);

    f32x4 acc[4][4];
    #pragma unroll
    for (int i = 0; i < 4; ++i)
        #pragma unroll
        for (int j = 0; j < 4; ++j)
            acc[i][j] = (f32x4){512.f, 512.f, 512.f, 512.f};   // monotonic bias

    unsigned best[4][4] = {};   // (biased bits & ~0x7FF) | (2047 - block-local col)

    const int k16r = (lr4 >> 1);
    const int odd  = lr4 & 1;

    for (int t = t0; t < t1; ++t) {
        const bool dt = (t == rs);              // diagonal tile
        #pragma unroll
        for (int ss = 0; ss < 8; ++ss) {        // K=32 slices
            __syncthreads();   // slice (t,ss) staged; prior reads of other slot done

            // prefetch next slice into the other slot (1 issue/thread)
            const int nt  = (ss < 7) ? t : t + 1;
            const int nss = (ss < 7) ? ss + 1 : 0;
            if (nt < t1)
                glds16(F8 + (size_t)(nt * 128 + (tid & 127)) * DIM
                           + nss * 32 + (tid >> 7) * 16,
                       &Bs[((ss & 1) ^ 1) * 4096 + tid * 16]);

            const long* __restrict__ Bl =
                reinterpret_cast<const long*>(Bs) + (ss & 1) * 512;

            long afv[4], bfv[4];
            #pragma unroll
            for (int i = 0; i < 4; ++i) {
                const int r = wrow + i * 16 + lc;
                afv[i] = Al[(ss * 2 + k16r) * 256 + r * 2 + odd];
            }
            #pragma unroll
            for (int j = 0; j < 4; ++j) {
                const int c = wcol + j * 16 + lc;
                bfv[j] = Bl[k16r * 256 + c * 2 + odd];
            }
            #pragma unroll
            for (int j = 0; j < 4; ++j)
                #pragma unroll
                for (int i = 0; i < 4; ++i)
                    acc[i][j] = __builtin_amdgcn_mfma_f32_16x16x32_fp8_fp8(
                        afv[i], bfv[j], acc[i][j], 0, 0, 0);
        }

        // ---- B-side fold: per-column max over the tile's 128 rows ----
        #pragma unroll
        for (int j = 0; j < 4; ++j) {
            unsigned kb = 0u;
            #pragma unroll
            for (int i = 0; i < 4; ++i)
                #pragma unroll
                for (int g = 0; g < 4; ++g) {
                    const int r_loc = wrow + i * 16 + lr4 * 4 + g;
                    unsigned key = (__float_as_uint(acc[i][j][g]) & 0xFFFFF800u)
                                   | (unsigned)(127 - r_loc);
                    if (dt && (wcol + j * 16 + lc == r_loc)) key = 0u;
                    kb = umax2(kb, key);
                }
            kb = umax2(kb, (unsigned)__shfl_xor((int)kb, 16));
            kb = umax2(kb, (unsigned)__shfl_xor((int)kb, 32));
            if (lr4 == 0) {    // 64-row half max -> one atomic per col per half
                const unsigned grow = (unsigned)row0 + (127u - (kb & 0x7FFu));
                const unsigned long long pk =
                    ((unsigned long long)(kb & 0xFFFFF800u) << 32) |
                    (0xFFFFFFFFu - grow);
                atomicMax(&scratch[((size_t)t * 128 + rs) * 128
                                   + wcol + j * 16 + lc], pk);
            }
        }

        // ---- A-side fold into running per-row argmax ----
        const int tl = t - t0;                   // block-local tile (<=15)
        unsigned cb[4];
        #pragma unroll
        for (int j = 0; j < 4; ++j)
            cb[j] = 2047u - (unsigned)(tl * 128 + wcol + j * 16 + lc);

        if (dt) {
            #pragma unroll
            for (int i = 0; i < 4; ++i)
                #pragma unroll
                for (int g = 0; g < 4; ++g) {
                    const int r_loc = wrow + i * 16 + lr4 * 4 + g;
                    unsigned bk = best[i][g];
                    #pragma unroll
                    for (int j = 0; j < 4; ++j) {
                        unsigned key = (__float_as_uint(acc[i][j][g])
                                        & 0xFFFFF800u) | cb[j];
                        if (wcol + j * 16 + lc == r_loc) key = 0u;
                        bk = umax2(bk, key);
                        acc[i][j][g] = 512.f;
                    }
                    best[i][g] = bk;
                }
        } else {
            #pragma unroll
            for (int i = 0; i < 4; ++i)
                #pragma unroll
                for (int g = 0; g < 4; ++g) {
                    const unsigned k0 = (__float_as_uint(acc[i][0][g]) & 0xFFFFF800u) | cb[0];
                    const unsigned k1 = (__float_as_uint(acc[i][1][g]) & 0xFFFFF800u) | cb[1];
                    const unsigned k2 = (__float_as_uint(acc[i][2][g]) & 0xFFFFF800u) | cb[2];
                    const unsigned k3 = (__float_as_uint(acc[i][3][g]) & 0xFFFFF800u) | cb[3];
                    best[i][g] = umax2(best[i][g],
                                       umax2(umax2(k0, k1), umax2(k2, k3)));
                    acc[i][0][g] = 512.f; acc[i][1][g] = 512.f;
                    acc[i][2][g] = 512.f; acc[i][3][g] = 512.f;
                }
        }
    }

    // ---- A-side: reduce over 16-lane col group, one u64 atomic per row ----
    #pragma unroll
    for (int i = 0; i < 4; ++i)
        #pragma unroll
        for (int g = 0; g < 4; ++g) {
            unsigned key = best[i][g];
            #pragma unroll
            for (int m = 8; m >= 1; m >>= 1)
                key = umax2(key, (unsigned)__shfl_xor((int)key, m));
            if (lc == 0) {
                const int r = row0 + wrow + i * 16 + lr4 * 4 + g;
                const unsigned c = (unsigned)(t0 * 128) + (2047u - (key & 0x7FFu));
                atomicMax(&packed[r],
                          ((unsigned long long)(key & 0xFFFFF800u) << 32) |
                          (0xFFFFFFFFu - c));
            }
        }
}

// -------- K1.5: coalesced scratch -> packed column-max scan --------
__global__ __launch_bounds__(256)
void scan_kernel(const unsigned long long* __restrict__ scratch,
                 unsigned long long* __restrict__ packed)
{
    const int t  = (int)blockIdx.x >> 2;       // stripe 0..127
    const int q  = (int)blockIdx.x & 3;        // quarter of panels
    const int c  = threadIdx.x & 127;
    const int h  = threadIdx.x >> 7;           // 0..1
    const int n  = t + 1;                      // valid panels rs = 0..t
    const int lo = (n * q) >> 2;
    const int hi = (n * (q + 1)) >> 2;
    unsigned long long m = 0ull;
    const unsigned long long* base = scratch + (size_t)t * 16384;
    for (int rs = lo + h; rs < hi; rs += 2)
        m = umax64(m, base[rs * 128 + c]);     // coalesced 1 KB rows
    if (m) atomicMax(&packed[t * 128 + c], m); // <=8 atomics per address
}

// -------- K2: exact fp32 distances + log terms (packed is final) --------
__global__ __launch_bounds__(256)
void dist_loss_kernel(const float* __restrict__ F,
                      const unsigned long long* __restrict__ packed,
                      double* __restrict__ partials)
{
    const int tid  = threadIdx.x;
    const int lane = tid & 63;
    const int w    = tid >> 6;
    const int gw   = blockIdx.x * 4 + w;       // 1024 waves
    double local = 0.0;
    for (int r = gw; r < NROWS; r += 1024) {
        const unsigned long long p = packed[r];
        const int idx = (int)(0xFFFFFFFFu - (unsigned)(p & 0xFFFFFFFFull));
        const float4 a = *reinterpret_cast<const float4*>(
            F + (size_t)r * DIM + (lane << 2));
        const float4 b = *reinterpret_cast<const float4*>(
            F + (size_t)idx * DIM + (lane << 2));
        const float dx = a.x - b.x + EPSF;
        const float dy = a.y - b.y + EPSF;
        const float dz = a.z - b.z + EPSF;
        const float dw = a.w - b.w + EPSF;
        float ss = dx * dx + dy * dy + dz * dz + dw * dw;
        #pragma unroll
        for (int m = 32; m >= 1; m >>= 1) ss += __shfl_xor(ss, m);
        if (lane == 0)
            local += 0.5 * log((double)ss) + log((double)NROWS);
    }
    __shared__ double sm[4];
    if (lane == 0) sm[w] = local;
    __syncthreads();
    if (tid == 0) partials[blockIdx.x] = sm[0] + sm[1] + sm[2] + sm[3];
}

__global__ __launch_bounds__(256)
void finalize_kernel(const double* __restrict__ partials, float* __restrict__ out)
{
    const int tid = threadIdx.x;
    double v = partials[tid];
    #pragma unroll
    for (int m = 32; m >= 1; m >>= 1) v += __shfl_xor(v, m);
    __shared__ double sm[4];
    if ((tid & 63) == 0) sm[tid >> 6] = v;
    __syncthreads();
    if (tid == 0) out[0] = (float)(-(sm[0] + sm[1] + sm[2] + sm[3]) / (double)NROWS);
}

extern "C" void kernel_launch(void* const* d_in, const int* in_sizes, int n_in,
                              void* d_out, int out_size, void* d_ws, size_t ws_size,
                              hipStream_t stream)
{
    const float* F   = (const float*)d_in[0];
    float*       out = (float*)d_out;

    char* ws = (char*)d_ws;
    unsigned char*      F8       = (unsigned char*)ws;                   // 4 MB
    unsigned long long* packed   = (unsigned long long*)(ws + 4194304);  // 128 KB
    unsigned long long* scratch  = (unsigned long long*)(ws + 4325376);  // 16 MB
    double*             partials = (double*)(ws + 21102592);             // 2 KB

    convert_kernel<<<2048, 256, 0, stream>>>(F, F8, packed, scratch);
    mfma_sym_fp8_kernel<<<1024, 256, 0, stream>>>(F8, packed, scratch);
    scan_kernel<<<512, 256, 0, stream>>>(scratch, packed);
    dist_loss_kernel<<<256, 256, 0, stream>>>(F, packed, partials);
    finalize_kernel<<<1, 256, 0, stream>>>(partials, out);
}

// Round 15
// 112.933 us; speedup vs baseline: 1.3969x; 1.3969x over previous
//
#include <hip/hip_runtime.h>
#include <hip/hip_bf16.h>
#include <math.h>

// Loss_26886495273741: uniformity loss
//   dots = F F^T (diag masked), I = argmax_row(dots), d = ||x - x_nn + eps||_2
//   loss = -mean(log(n*d))
// F: [16384, 256] fp32.
//
// Round 15: occupancy retry, de-confounded. R14 failed because
//   __launch_bounds__(256,4) capped VGPR at 64 -> spills (WRITE 131MB).
//   This round: LDS 40960 (A 32KB + B 2x4KB K=32 dbuf) -> 4 blocks/CU by
//   RESOURCE math, with the R8/R13-proven __launch_bounds__(256,3) so the
//   allocator keeps VGPR ~80 (<=128 still allows 4 waves/SIMD).
//   Full grid resident (1024 = 4x256) -> R9's balanced kgen remap so every
//   CU's 4 blocks sum to ~equal tile counts (else 1.6x makespan skew).
//   All folds / atomics / K0 / scan / K2 are R13-verbatim.

#define NROWS 16384
#define DIM   256
#define EPSF  1e-6f

typedef __attribute__((ext_vector_type(4))) float f32x4;

typedef const __attribute__((address_space(1))) void* gas1_t;
typedef __attribute__((address_space(3))) void* las3_t;

__device__ __forceinline__ void glds16(const void* g, void* l) {
    __builtin_amdgcn_global_load_lds((gas1_t)g, (las3_t)l, 16, 0, 0);
}

__device__ __forceinline__ unsigned umax2(unsigned a, unsigned b) {
    return a > b ? a : b;
}

__device__ __forceinline__ unsigned long long umax64(unsigned long long a,
                                                     unsigned long long b) {
    return a > b ? a : b;
}

// RNE fp32 -> OCP e4m3fn (subnormal cutoff at 2^-6; codes continuous at seam)
__device__ __forceinline__ unsigned f2e4m3(float f) {
    union { float f; unsigned u; } x; x.f = f;
    const unsigned s = (x.u >> 24) & 0x80u;
    const unsigned au = x.u & 0x7FFFFFFFu;
    const float af = __uint_as_float(au);
    if (au < 0x3C800000u) {                    // |x| < 2^-6: subnormal region
        const int q = (int)(af * 512.0f + 0.5f);   // LSB = 2^-9
        return s | (unsigned)q;
    }
    const unsigned add = 0x7FFFFu + ((au >> 20) & 1u);
    const unsigned v = au + add;
    const unsigned e = (v >> 23) - 120u;       // e4m3 exponent (bias 7), e>=1
    return s | (e << 3) | ((v >> 20) & 7u);
}

// -------- K0: convert fp32 -> fp8 e4m3, zero packed + scratch --------
__global__ __launch_bounds__(256)
void convert_kernel(const float* __restrict__ F, unsigned char* __restrict__ F8,
                    unsigned long long* __restrict__ packed,
                    unsigned long long* __restrict__ scratch)
{
    const int t = blockIdx.x * 256 + threadIdx.x;     // 524288 threads
    const float4 a = *reinterpret_cast<const float4*>(F + (size_t)t * 8);
    const float4 b = *reinterpret_cast<const float4*>(F + (size_t)t * 8 + 4);
    const unsigned lo = f2e4m3(a.x) | (f2e4m3(a.y) << 8) |
                        (f2e4m3(a.z) << 16) | (f2e4m3(a.w) << 24);
    const unsigned hi = f2e4m3(b.x) | (f2e4m3(b.y) << 8) |
                        (f2e4m3(b.z) << 16) | (f2e4m3(b.w) << 24);
    uint2 v; v.x = lo; v.y = hi;
    *reinterpret_cast<uint2*>(F8 + (size_t)t * 8) = v;
    if (t < NROWS) packed[t] = 0ull;
    #pragma unroll
    for (int q = 0; q < 4; ++q)                       // 2M u64 = 16 MB
        scratch[(size_t)t * 4 + q] = 0ull;
}

// -------- K1: symmetric fp8 MFMA + two-sided argmax (K=32, 4 blk/CU) --------
__global__ __launch_bounds__(256, 3)
void mfma_sym_fp8_kernel(const unsigned char* __restrict__ F8,
                         unsigned long long* __restrict__ packed,
                         unsigned long long* __restrict__ scratch)
{
    __shared__ __align__(16) unsigned char As[32768];   // [k16 0..15][row][16B]
    __shared__ __align__(16) unsigned char Bs[2 * 4096];// 2 x [k16 0..1][col][16B]

    const int tid = threadIdx.x;
    const int w   = tid >> 6;
    const int l   = tid & 63;

    // balanced remap: each CU's 4 resident generations sum to ~equal work
    const int bid  = (int)blockIdx.x;
    const int kgen = bid >> 8;            // 0..3
    const int m5   = (bid >> 3) & 31;     // 0..31
    const int ck   = bid & 7;             // chunk-of-stripe
    const int rs   = (kgen == 0) ? m5 :
                     (kgen == 1) ? 63 - m5 :
                     (kgen == 2) ? 64 + m5 : 127 - m5;
    const int span = 128 - rs;
    const int t0   = rs + ((span * ck) >> 3);
    const int t1   = rs + ((span * (ck + 1)) >> 3);
    if (t0 >= t1) return;                 // block-uniform

    const int row0 = rs * 128;
    const int wrow = (w >> 1) * 64;
    const int wcol = (w & 1) * 64;
    const int lc   = l & 15;
    const int lr4  = l >> 4;

    // ---- stage A panel: 32 issues, cell q*64+l -> [k16=q>>1][row=(q&1)*64+l] ----
    #pragma unroll
    for (int m = 0; m < 8; ++m) {
        const int q   = 8 * w + m;              // 0..31
        const int k16 = q >> 1;
        const int row = (q & 1) * 64 + l;
        glds16(F8 + (size_t)(row0 + row) * DIM + k16 * 16, &As[q * 1024]);
    }

    // ---- stage first B slice (t0, slice 0) into slot 0: 1 issue/thread ----
    glds16(F8 + (size_t)(t0 * 128 + (tid & 127)) * DIM + (tid >> 7) * 16,
           &Bs[tid * 16]);

    const long* __restrict__ Al = reinterpret_cast<const long*>(As);

    f32x4 acc[4][4];
    #pragma unroll
    for (int i = 0; i < 4; ++i)
        #pragma unroll
        for (int j = 0; j < 4; ++j)
            acc[i][j] = (f32x4){512.f, 512.f, 512.f, 512.f};   // monotonic bias

    unsigned best[4][4] = {};   // (biased bits & ~0x7FF) | (2047 - block-local col)

    const int k16r = (lr4 >> 1);
    const int odd  = lr4 & 1;

    for (int t = t0; t < t1; ++t) {
        const bool dt = (t == rs);              // diagonal tile
        #pragma unroll
        for (int ss = 0; ss < 8; ++ss) {        // K=32 slices
            __syncthreads();   // slice (t,ss) staged; prior reads of other slot done

            // prefetch next slice into the other slot (1 issue/thread)
            const int nt  = (ss < 7) ? t : t + 1;
            const int nss = (ss < 7) ? ss + 1 : 0;
            if (nt < t1)
                glds16(F8 + (size_t)(nt * 128 + (tid & 127)) * DIM
                           + nss * 32 + (tid >> 7) * 16,
                       &Bs[((ss & 1) ^ 1) * 4096 + tid * 16]);

            const long* __restrict__ Bl =
                reinterpret_cast<const long*>(Bs) + (ss & 1) * 512;

            long afv[4], bfv[4];
            #pragma unroll
            for (int i = 0; i < 4; ++i) {
                const int r = wrow + i * 16 + lc;
                afv[i] = Al[(ss * 2 + k16r) * 256 + r * 2 + odd];
            }
            #pragma unroll
            for (int j = 0; j < 4; ++j) {
                const int c = wcol + j * 16 + lc;
                bfv[j] = Bl[k16r * 256 + c * 2 + odd];
            }
            #pragma unroll
            for (int j = 0; j < 4; ++j)
                #pragma unroll
                for (int i = 0; i < 4; ++i)
                    acc[i][j] = __builtin_amdgcn_mfma_f32_16x16x32_fp8_fp8(
                        afv[i], bfv[j], acc[i][j], 0, 0, 0);
        }

        // ---- B-side fold: per-column max over the tile's 128 rows ----
        #pragma unroll
        for (int j = 0; j < 4; ++j) {
            unsigned kb = 0u;
            #pragma unroll
            for (int i = 0; i < 4; ++i)
                #pragma unroll
                for (int g = 0; g < 4; ++g) {
                    const int r_loc = wrow + i * 16 + lr4 * 4 + g;
                    unsigned key = (__float_as_uint(acc[i][j][g]) & 0xFFFFF800u)
                                   | (unsigned)(127 - r_loc);
                    if (dt && (wcol + j * 16 + lc == r_loc)) key = 0u;
                    kb = umax2(kb, key);
                }
            kb = umax2(kb, (unsigned)__shfl_xor((int)kb, 16));
            kb = umax2(kb, (unsigned)__shfl_xor((int)kb, 32));
            if (lr4 == 0) {    // 64-row half max -> one atomic per col per half
                const unsigned grow = (unsigned)row0 + (127u - (kb & 0x7FFu));
                const unsigned long long pk =
                    ((unsigned long long)(kb & 0xFFFFF800u) << 32) |
                    (0xFFFFFFFFu - grow);
                atomicMax(&scratch[((size_t)t * 128 + rs) * 128
                                   + wcol + j * 16 + lc], pk);
            }
        }

        // ---- A-side fold into running per-row argmax ----
        const int tl = t - t0;                   // block-local tile (<=15)
        unsigned cb[4];
        #pragma unroll
        for (int j = 0; j < 4; ++j)
            cb[j] = 2047u - (unsigned)(tl * 128 + wcol + j * 16 + lc);

        if (dt) {
            #pragma unroll
            for (int i = 0; i < 4; ++i)
                #pragma unroll
                for (int g = 0; g < 4; ++g) {
                    const int r_loc = wrow + i * 16 + lr4 * 4 + g;
                    unsigned bk = best[i][g];
                    #pragma unroll
                    for (int j = 0; j < 4; ++j) {
                        unsigned key = (__float_as_uint(acc[i][j][g])
                                        & 0xFFFFF800u) | cb[j];
                        if (wcol + j * 16 + lc == r_loc) key = 0u;
                        bk = umax2(bk, key);
                        acc[i][j][g] = 512.f;
                    }
                    best[i][g] = bk;
                }
        } else {
            #pragma unroll
            for (int i = 0; i < 4; ++i)
                #pragma unroll
                for (int g = 0; g < 4; ++g) {
                    const unsigned k0 = (__float_as_uint(acc[i][0][g]) & 0xFFFFF800u) | cb[0];
                    const unsigned k1 = (__float_as_uint(acc[i][1][g]) & 0xFFFFF800u) | cb[1];
                    const unsigned k2 = (__float_as_uint(acc[i][2][g]) & 0xFFFFF800u) | cb[2];
                    const unsigned k3 = (__float_as_uint(acc[i][3][g]) & 0xFFFFF800u) | cb[3];
                    best[i][g] = umax2(best[i][g],
                                       umax2(umax2(k0, k1), umax2(k2, k3)));
                    acc[i][0][g] = 512.f; acc[i][1][g] = 512.f;
                    acc[i][2][g] = 512.f; acc[i][3][g] = 512.f;
                }
        }
    }

    // ---- A-side: reduce over 16-lane col group, one u64 atomic per row ----
    #pragma unroll
    for (int i = 0; i < 4; ++i)
        #pragma unroll
        for (int g = 0; g < 4; ++g) {
            unsigned key = best[i][g];
            #pragma unroll
            for (int m = 8; m >= 1; m >>= 1)
                key = umax2(key, (unsigned)__shfl_xor((int)key, m));
            if (lc == 0) {
                const int r = row0 + wrow + i * 16 + lr4 * 4 + g;
                const unsigned c = (unsigned)(t0 * 128) + (2047u - (key & 0x7FFu));
                atomicMax(&packed[r],
                          ((unsigned long long)(key & 0xFFFFF800u) << 32) |
                          (0xFFFFFFFFu - c));
            }
        }
}

// -------- K1.5: coalesced scratch -> packed column-max scan --------
__global__ __launch_bounds__(256)
void scan_kernel(const unsigned long long* __restrict__ scratch,
                 unsigned long long* __restrict__ packed)
{
    const int t  = (int)blockIdx.x >> 2;       // stripe 0..127
    const int q  = (int)blockIdx.x & 3;        // quarter of panels
    const int c  = threadIdx.x & 127;
    const int h  = threadIdx.x >> 7;           // 0..1
    const int n  = t + 1;                      // valid panels rs = 0..t
    const int lo = (n * q) >> 2;
    const int hi = (n * (q + 1)) >> 2;
    unsigned long long m = 0ull;
    const unsigned long long* base = scratch + (size_t)t * 16384;
    for (int rs = lo + h; rs < hi; rs += 2)
        m = umax64(m, base[rs * 128 + c]);     // coalesced 1 KB rows
    if (m) atomicMax(&packed[t * 128 + c], m); // <=8 atomics per address
}

// -------- K2: exact fp32 distances + log terms (packed is final) --------
__global__ __launch_bounds__(256)
void dist_loss_kernel(const float* __restrict__ F,
                      const unsigned long long* __restrict__ packed,
                      double* __restrict__ partials)
{
    const int tid  = threadIdx.x;
    const int lane = tid & 63;
    const int w    = tid >> 6;
    const int gw   = blockIdx.x * 4 + w;       // 1024 waves
    double local = 0.0;
    for (int r = gw; r < NROWS; r += 1024) {
        const unsigned long long p = packed[r];
        const int idx = (int)(0xFFFFFFFFu - (unsigned)(p & 0xFFFFFFFFull));
        const float4 a = *reinterpret_cast<const float4*>(
            F + (size_t)r * DIM + (lane << 2));
        const float4 b = *reinterpret_cast<const float4*>(
            F + (size_t)idx * DIM + (lane << 2));
        const float dx = a.x - b.x + EPSF;
        const float dy = a.y - b.y + EPSF;
        const float dz = a.z - b.z + EPSF;
        const float dw = a.w - b.w + EPSF;
        float ss = dx * dx + dy * dy + dz * dz + dw * dw;
        #pragma unroll
        for (int m = 32; m >= 1; m >>= 1) ss += __shfl_xor(ss, m);
        if (lane == 0)
            local += 0.5 * log((double)ss) + log((double)NROWS);
    }
    __shared__ double sm[4];
    if (lane == 0) sm[w] = local;
    __syncthreads();
    if (tid == 0) partials[blockIdx.x] = sm[0] + sm[1] + sm[2] + sm[3];
}

__global__ __launch_bounds__(256)
void finalize_kernel(const double* __restrict__ partials, float* __restrict__ out)
{
    const int tid = threadIdx.x;
    double v = partials[tid];
    #pragma unroll
    for (int m = 32; m >= 1; m >>= 1) v += __shfl_xor(v, m);
    __shared__ double sm[4];
    if ((tid & 63) == 0) sm[tid >> 6] = v;
    __syncthreads();
    if (tid == 0) out[0] = (float)(-(sm[0] + sm[1] + sm[2] + sm[3]) / (double)NROWS);
}

extern "C" void kernel_launch(void* const* d_in, const int* in_sizes, int n_in,
                              void* d_out, int out_size, void* d_ws, size_t ws_size,
                              hipStream_t stream)
{
    const float* F   = (const float*)d_in[0];
    float*       out = (float*)d_out;

    char* ws = (char*)d_ws;
    unsigned char*      F8       = (unsigned char*)ws;                   // 4 MB
    unsigned long long* packed   = (unsigned long long*)(ws + 4194304);  // 128 KB
    unsigned long long* scratch  = (unsigned long long*)(ws + 4325376);  // 16 MB
    double*             partials = (double*)(ws + 21102592);             // 2 KB

    convert_kernel<<<2048, 256, 0, stream>>>(F, F8, packed, scratch);
    mfma_sym_fp8_kernel<<<1024, 256, 0, stream>>>(F8, packed, scratch);
    scan_kernel<<<512, 256, 0, stream>>>(scratch, packed);
    dist_loss_kernel<<<256, 256, 0, stream>>>(F, packed, partials);
    finalize_kernel<<<1, 256, 0, stream>>>(partials, out);
}

// Round 16
// 104.310 us; speedup vs baseline: 1.5123x; 1.0827x over previous
//
#include <hip/hip_runtime.h>
#include <hip/hip_bf16.h>
#include <math.h>

// Loss_26886495273741: uniformity loss
//   dots = F F^T (diag masked), I = argmax_row(dots), d = ||x - x_nn + eps||_2
//   loss = -mean(log(n*d))
// F: [16384, 256] fp32.
//
// Round 16 (final): R13 protected. Hot loop (K1) is byte-identical to the
//   measured-79us R8/R13 chassis -- 0/8 structural experiments beat it
//   (counted-vmcnt x2, af-persist x3, ring, deferred stores, 4-blk/CU x2).
//   Only change: K0 zeroes just the rs<=t half of scratch (the only region
//   K1 atomicMax-es into and scan reads; rs>t is never touched), ~8MB fewer
//   stores. Residual K1 profile: MfmaUtil 35% / VALU 35% / HBM 6% -- the
//   2-phase barrier-drain plateau (m233); breaking it needs the full
//   8-phase co-design, every graft of which regressed on this kernel.

#define NROWS 16384
#define DIM   256
#define EPSF  1e-6f

typedef __attribute__((ext_vector_type(4))) float f32x4;

typedef const __attribute__((address_space(1))) void* gas1_t;
typedef __attribute__((address_space(3))) void* las3_t;

__device__ __forceinline__ void glds16(const void* g, void* l) {
    __builtin_amdgcn_global_load_lds((gas1_t)g, (las3_t)l, 16, 0, 0);
}

__device__ __forceinline__ unsigned umax2(unsigned a, unsigned b) {
    return a > b ? a : b;
}

__device__ __forceinline__ unsigned long long umax64(unsigned long long a,
                                                     unsigned long long b) {
    return a > b ? a : b;
}

// RNE fp32 -> OCP e4m3fn (subnormal cutoff at 2^-6; codes continuous at seam)
__device__ __forceinline__ unsigned f2e4m3(float f) {
    union { float f; unsigned u; } x; x.f = f;
    const unsigned s = (x.u >> 24) & 0x80u;
    const unsigned au = x.u & 0x7FFFFFFFu;
    const float af = __uint_as_float(au);
    if (au < 0x3C800000u) {                    // |x| < 2^-6: subnormal region
        const int q = (int)(af * 512.0f + 0.5f);   // LSB = 2^-9
        return s | (unsigned)q;
    }
    const unsigned add = 0x7FFFFu + ((au >> 20) & 1u);
    const unsigned v = au + add;
    const unsigned e = (v >> 23) - 120u;       // e4m3 exponent (bias 7), e>=1
    return s | (e << 3) | ((v >> 20) & 7u);
}

// -------- K0: convert fp32 -> fp8 e4m3, zero packed + used scratch --------
__global__ __launch_bounds__(256)
void convert_kernel(const float* __restrict__ F, unsigned char* __restrict__ F8,
                    unsigned long long* __restrict__ packed,
                    unsigned long long* __restrict__ scratch)
{
    const int t = blockIdx.x * 256 + threadIdx.x;     // 524288 threads
    const float4 a = *reinterpret_cast<const float4*>(F + (size_t)t * 8);
    const float4 b = *reinterpret_cast<const float4*>(F + (size_t)t * 8 + 4);
    const unsigned lo = f2e4m3(a.x) | (f2e4m3(a.y) << 8) |
                        (f2e4m3(a.z) << 16) | (f2e4m3(a.w) << 24);
    const unsigned hi = f2e4m3(b.x) | (f2e4m3(b.y) << 8) |
                        (f2e4m3(b.z) << 16) | (f2e4m3(b.w) << 24);
    uint2 v; v.x = lo; v.y = hi;
    *reinterpret_cast<uint2*>(F8 + (size_t)t * 8) = v;
    if (t < NROWS) packed[t] = 0ull;
    // zero only scratch[tt][rsx][c] with rsx <= tt (the region K1 writes and
    // scan reads; rsx > tt is never touched by either)
    #pragma unroll
    for (int q = 0; q < 4; ++q) {                     // 2M u64 total
        const size_t i  = (size_t)t * 4 + q;
        const int tt  = (int)(i >> 14);               // stripe 0..127
        const int rsx = (int)(i >> 7) & 127;          // panel row
        if (rsx <= tt) scratch[i] = 0ull;
    }
}

// -------- K1: symmetric fp8 MFMA + two-sided argmax (R8/R13 verbatim) --------
__global__ __launch_bounds__(256, 3)
void mfma_sym_fp8_kernel(const unsigned char* __restrict__ F8,
                         unsigned long long* __restrict__ packed,
                         unsigned long long* __restrict__ scratch)
{
    __shared__ __align__(16) unsigned char As[32768];   // [k16][row][16B]
    __shared__ __align__(16) unsigned char Bs[2 * 8192];// 2 x [k16][col][16B]

    const int tid  = threadIdx.x;
    const int w    = tid >> 6;
    const int l    = tid & 63;
    const int rs   = (int)blockIdx.x >> 3;      // row stripe 0..127
    const int ck   = (int)blockIdx.x & 7;       // chunk-of-stripe 0..7
    const int span = 128 - rs;
    const int t0   = rs + (span * ck) / 8;
    const int t1   = rs + (span * (ck + 1)) / 8;
    if (t0 >= t1) return;                       // block-uniform

    const int row0 = rs * 128;
    const int wrow = (w >> 1) * 64;
    const int wcol = (w & 1) * 64;
    const int lc   = l & 15;
    const int lr4  = l >> 4;

    // ---- stage A panel: 32 issues, cell q*64+l -> [k16=q>>1][row=(q&1)*64+l] ----
    #pragma unroll
    for (int m = 0; m < 8; ++m) {
        const int q   = 8 * w + m;              // 0..31
        const int k16 = q >> 1;
        const int row = (q & 1) * 64 + l;
        glds16(F8 + (size_t)(row0 + row) * DIM + k16 * 16, &As[q * 1024]);
    }

    // ---- stage first B slice (t0, slice 0) into slot 0 ----
    #pragma unroll
    for (int q2 = 0; q2 < 2; ++q2) {
        const int col = q2 * 64 + l;
        glds16(F8 + (size_t)(t0 * 128 + col) * DIM + w * 16,
               &Bs[(2 * w + q2) * 1024]);
    }

    const long* __restrict__ Al = reinterpret_cast<const long*>(As);

    f32x4 acc[4][4];
    #pragma unroll
    for (int i = 0; i < 4; ++i)
        #pragma unroll
        for (int j = 0; j < 4; ++j)
            acc[i][j] = (f32x4){512.f, 512.f, 512.f, 512.f};   // monotonic bias

    unsigned best[4][4] = {};   // (biased bits & ~0x7FF) | (2047 - block-local col)

    const int k16r = (lr4 >> 1);
    const int odd  = lr4 & 1;

    for (int t = t0; t < t1; ++t) {
        const bool dt = (t == rs);              // diagonal tile
        #pragma unroll
        for (int ss = 0; ss < 4; ++ss) {        // K=64 slices
            __syncthreads();   // slice (t,ss) staged; prior reads of other slot done

            // prefetch next slice into the other slot
            const int nt  = (ss < 3) ? t : t + 1;
            const int nss = (ss < 3) ? ss + 1 : 0;
            if (nt < t1) {
                #pragma unroll
                for (int q2 = 0; q2 < 2; ++q2) {
                    const int col = q2 * 64 + l;
                    glds16(F8 + (size_t)(nt * 128 + col) * DIM + nss * 64 + w * 16,
                           &Bs[((ss & 1) ^ 1) * 8192 + (2 * w + q2) * 1024]);
                }
            }

            const long* __restrict__ Bl =
                reinterpret_cast<const long*>(Bs) + (ss & 1) * 1024;

            #pragma unroll
            for (int h = 0; h < 2; ++h) {       // two K=32 MFMA steps
                const int kk = h * 2 + k16r;    // slice-local k16 0..3
                long afv[4], bfv[4];
                #pragma unroll
                for (int i = 0; i < 4; ++i) {
                    const int r = wrow + i * 16 + lc;
                    afv[i] = Al[(ss * 4 + kk) * 256 + r * 2 + odd];
                }
                #pragma unroll
                for (int j = 0; j < 4; ++j) {
                    const int c = wcol + j * 16 + lc;
                    bfv[j] = Bl[kk * 256 + c * 2 + odd];
                }
                #pragma unroll
                for (int j = 0; j < 4; ++j)
                    #pragma unroll
                    for (int i = 0; i < 4; ++i)
                        acc[i][j] = __builtin_amdgcn_mfma_f32_16x16x32_fp8_fp8(
                            afv[i], bfv[j], acc[i][j], 0, 0, 0);
            }
        }

        // ---- B-side fold: per-column max over the tile's 128 rows ----
        #pragma unroll
        for (int j = 0; j < 4; ++j) {
            unsigned kb = 0u;
            #pragma unroll
            for (int i = 0; i < 4; ++i)
                #pragma unroll
                for (int g = 0; g < 4; ++g) {
                    const int r_loc = wrow + i * 16 + lr4 * 4 + g;
                    unsigned key = (__float_as_uint(acc[i][j][g]) & 0xFFFFF800u)
                                   | (unsigned)(127 - r_loc);
                    if (dt && (wcol + j * 16 + lc == r_loc)) key = 0u;
                    kb = umax2(kb, key);
                }
            kb = umax2(kb, (unsigned)__shfl_xor((int)kb, 16));
            kb = umax2(kb, (unsigned)__shfl_xor((int)kb, 32));
            if (lr4 == 0) {    // 64-row half max -> one atomic per col per half
                const unsigned grow = (unsigned)row0 + (127u - (kb & 0x7FFu));
                const unsigned long long pk =
                    ((unsigned long long)(kb & 0xFFFFF800u) << 32) |
                    (0xFFFFFFFFu - grow);
                atomicMax(&scratch[((size_t)t * 128 + rs) * 128
                                   + wcol + j * 16 + lc], pk);
            }
        }

        // ---- A-side fold into running per-row argmax ----
        const int tl = t - t0;                   // block-local tile (<=15)
        unsigned cb[4];
        #pragma unroll
        for (int j = 0; j < 4; ++j)
            cb[j] = 2047u - (unsigned)(tl * 128 + wcol + j * 16 + lc);

        if (dt) {
            #pragma unroll
            for (int i = 0; i < 4; ++i)
                #pragma unroll
                for (int g = 0; g < 4; ++g) {
                    const int r_loc = wrow + i * 16 + lr4 * 4 + g;
                    unsigned bk = best[i][g];
                    #pragma unroll
                    for (int j = 0; j < 4; ++j) {
                        unsigned key = (__float_as_uint(acc[i][j][g])
                                        & 0xFFFFF800u) | cb[j];
                        if (wcol + j * 16 + lc == r_loc) key = 0u;
                        bk = umax2(bk, key);
                        acc[i][j][g] = 512.f;
                    }
                    best[i][g] = bk;
                }
        } else {
            #pragma unroll
            for (int i = 0; i < 4; ++i)
                #pragma unroll
                for (int g = 0; g < 4; ++g) {
                    const unsigned k0 = (__float_as_uint(acc[i][0][g]) & 0xFFFFF800u) | cb[0];
                    const unsigned k1 = (__float_as_uint(acc[i][1][g]) & 0xFFFFF800u) | cb[1];
                    const unsigned k2 = (__float_as_uint(acc[i][2][g]) & 0xFFFFF800u) | cb[2];
                    const unsigned k3 = (__float_as_uint(acc[i][3][g]) & 0xFFFFF800u) | cb[3];
                    best[i][g] = umax2(best[i][g],
                                       umax2(umax2(k0, k1), umax2(k2, k3)));
                    acc[i][0][g] = 512.f; acc[i][1][g] = 512.f;
                    acc[i][2][g] = 512.f; acc[i][3][g] = 512.f;
                }
        }
    }

    // ---- A-side: reduce over 16-lane col group, one u64 atomic per row ----
    #pragma unroll
    for (int i = 0; i < 4; ++i)
        #pragma unroll
        for (int g = 0; g < 4; ++g) {
            unsigned key = best[i][g];
            #pragma unroll
            for (int m = 8; m >= 1; m >>= 1)
                key = umax2(key, (unsigned)__shfl_xor((int)key, m));
            if (lc == 0) {
                const int r = row0 + wrow + i * 16 + lr4 * 4 + g;
                const unsigned c = (unsigned)(t0 * 128) + (2047u - (key & 0x7FFu));
                atomicMax(&packed[r],
                          ((unsigned long long)(key & 0xFFFFF800u) << 32) |
                          (0xFFFFFFFFu - c));
            }
        }
}

// -------- K1.5: coalesced scratch -> packed column-max scan --------
__global__ __launch_bounds__(256)
void scan_kernel(const unsigned long long* __restrict__ scratch,
                 unsigned long long* __restrict__ packed)
{
    const int t  = (int)blockIdx.x >> 2;       // stripe 0..127
    const int q  = (int)blockIdx.x & 3;        // quarter of panels
    const int c  = threadIdx.x & 127;
    const int h  = threadIdx.x >> 7;           // 0..1
    const int n  = t + 1;                      // valid panels rs = 0..t
    const int lo = (n * q) >> 2;
    const int hi = (n * (q + 1)) >> 2;
    unsigned long long m = 0ull;
    const unsigned long long* base = scratch + (size_t)t * 16384;
    for (int rs = lo + h; rs < hi; rs += 2)
        m = umax64(m, base[rs * 128 + c]);     // coalesced 1 KB rows
    if (m) atomicMax(&packed[t * 128 + c], m); // <=8 atomics per address
}

// -------- K2: exact fp32 distances + log terms (packed is final) --------
__global__ __launch_bounds__(256)
void dist_loss_kernel(const float* __restrict__ F,
                      const unsigned long long* __restrict__ packed,
                      double* __restrict__ partials)
{
    const int tid  = threadIdx.x;
    const int lane = tid & 63;
    const int w    = tid >> 6;
    const int gw   = blockIdx.x * 4 + w;       // 1024 waves
    double local = 0.0;
    for (int r = gw; r < NROWS; r += 1024) {
        const unsigned long long p = packed[r];
        const int idx = (int)(0xFFFFFFFFu - (unsigned)(p & 0xFFFFFFFFull));
        const float4 a = *reinterpret_cast<const float4*>(
            F + (size_t)r * DIM + (lane << 2));
        const float4 b = *reinterpret_cast<const float4*>(
            F + (size_t)idx * DIM + (lane << 2));
        const float dx = a.x - b.x + EPSF;
        const float dy = a.y - b.y + EPSF;
        const float dz = a.z - b.z + EPSF;
        const float dw = a.w - b.w + EPSF;
        float ss = dx * dx + dy * dy + dz * dz + dw * dw;
        #pragma unroll
        for (int m = 32; m >= 1; m >>= 1) ss += __shfl_xor(ss, m);
        if (lane == 0)
            local += 0.5 * log((double)ss) + log((double)NROWS);
    }
    __shared__ double sm[4];
    if (lane == 0) sm[w] = local;
    __syncthreads();
    if (tid == 0) partials[blockIdx.x] = sm[0] + sm[1] + sm[2] + sm[3];
}

__global__ __launch_bounds__(256)
void finalize_kernel(const double* __restrict__ partials, float* __restrict__ out)
{
    const int tid = threadIdx.x;
    double v = partials[tid];
    #pragma unroll
    for (int m = 32; m >= 1; m >>= 1) v += __shfl_xor(v, m);
    __shared__ double sm[4];
    if ((tid & 63) == 0) sm[tid >> 6] = v;
    __syncthreads();
    if (tid == 0) out[0] = (float)(-(sm[0] + sm[1] + sm[2] + sm[3]) / (double)NROWS);
}

extern "C" void kernel_launch(void* const* d_in, const int* in_sizes, int n_in,
                              void* d_out, int out_size, void* d_ws, size_t ws_size,
                              hipStream_t stream)
{
    const float* F   = (const float*)d_in[0];
    float*       out = (float*)d_out;

    char* ws = (char*)d_ws;
    unsigned char*      F8       = (unsigned char*)ws;                   // 4 MB
    unsigned long long* packed   = (unsigned long long*)(ws + 4194304);  // 128 KB
    unsigned long long* scratch  = (unsigned long long*)(ws + 4325376);  // 16 MB
    double*             partials = (double*)(ws + 21102592);             // 2 KB

    convert_kernel<<<2048, 256, 0, stream>>>(F, F8, packed, scratch);
    mfma_sym_fp8_kernel<<<1024, 256, 0, stream>>>(F8, packed, scratch);
    scan_kernel<<<512, 256, 0, stream>>>(scratch, packed);
    dist_loss_kernel<<<256, 256, 0, stream>>>(F, packed, partials);
    finalize_kernel<<<1, 256, 0, stream>>>(partials, out);
}